// Round 11
// baseline (168.196 us; speedup 1.0000x reference)
//
#include <hip/hip_runtime.h>

#define B_ 32
#define S_ 64
#define H_ 300
#define H2_ 600
#define L_ 20
#define ROW_ 160                    // 8 pieces * 20
#define OUTQ_OFF ((size_t)B_ * S_ * ROW_)
#define NEG_INF -3.402823466e38f

#define NB_COS 1024                 // 64 bd * 16 pg (4 p-rows each)
#define NB_W 188                    // 48000 / 256 rounded up
#define NB_MP 1280                  // 64 bd * 20 l
#define NB_OUT 1024                 // 64 bd * 16 sg

typedef __attribute__((ext_vector_type(8))) _Float16 half8v;   // 8 f16 = 4 VGPRs
typedef __attribute__((ext_vector_type(4))) _Float16 half4v;   // 4 f16 = 8 B
typedef __attribute__((ext_vector_type(4))) float float4v;

// ---------------- cos block: (bd, pg) -> 4 p-rows x 64 q, norms in-block.
// EXACT r9/r10-verified version.
struct CosS {                       // 19008 B -> kernel A alloc -> 8 blocks/CU
  float xq[S_][65];                 // stride 65: 2-way scalar reads (free)
  float xp[4][68];                  // 272 B rows, 16-B aligned, broadcast b128
  float qn_l[S_];
  float cp[4][S_];
};

__device__ __forceinline__ void cos_body(char* smem, int bid,
                                         const float* __restrict__ P,
                                         const float* __restrict__ Q,
                                         float* __restrict__ cosM,
                                         float* __restrict__ sumpart,
                                         float* __restrict__ sum_q) {
  CosS& S = *(CosS*)smem;
  int bd = bid >> 4, pg = bid & 15;
  int b = bd >> 1, dir = bd & 1;
  int t = threadIdx.x;
  int q = t & 63, pr = t >> 6;
  const float* Pb = P + (size_t)b * S_ * H2_ + dir * H_;
  const float* Qb = Q + (size_t)b * S_ * H2_ + dir * H_;
  float dot = 0.f, np2 = 0.f, nq2 = 0.f;
  for (int c0 = 0; c0 < H_; c0 += 64) {          // 5 chunks (last zero-padded)
    __syncthreads();
#pragma unroll
    for (int jj = 0; jj < 4; ++jj) {             // 64 rows x 16 groups static
      int idx = t + 256 * jj;
      int s = idx >> 4, g = idx & 15;
      int h = c0 + 4 * g;
      float4v v = {0.f, 0.f, 0.f, 0.f};
      if (h < 297) v = *(const float4v*)&Qb[(size_t)s * H2_ + h];
      S.xq[s][4 * g + 0] = v.x; S.xq[s][4 * g + 1] = v.y;
      S.xq[s][4 * g + 2] = v.z; S.xq[s][4 * g + 3] = v.w;
    }
    if (t < 64) {                                // 4 rows x 16 groups static
      int s = t >> 4, g = t & 15;
      int h = c0 + 4 * g;
      float4v v = {0.f, 0.f, 0.f, 0.f};
      if (h < 297) v = *(const float4v*)&Pb[(size_t)(pg * 4 + s) * H2_ + h];
      *(float4v*)&S.xp[s][4 * g] = v;
    }
    __syncthreads();
    for (int hh = 0; hh < 64; hh += 4) {
      float4v av = *(const float4v*)&S.xp[pr][hh];       // wave-broadcast (free)
      float q0 = S.xq[q][hh + 0];
      float q1 = S.xq[q][hh + 1];
      float q2 = S.xq[q][hh + 2];
      float q3 = S.xq[q][hh + 3];
      dot = fmaf(av.x, q0, dot); dot = fmaf(av.y, q1, dot);
      dot = fmaf(av.z, q2, dot); dot = fmaf(av.w, q3, dot);
      np2 = fmaf(av.x, av.x, np2); np2 = fmaf(av.y, av.y, np2);
      np2 = fmaf(av.z, av.z, np2); np2 = fmaf(av.w, av.w, np2);
      if (pr == 0) {                                     // wave-uniform branch
        nq2 = fmaf(q0, q0, nq2); nq2 = fmaf(q1, q1, nq2);
        nq2 = fmaf(q2, q2, nq2); nq2 = fmaf(q3, q3, nq2);
      }
    }
  }
  if (pr == 0) S.qn_l[q] = sqrtf(nq2);
  __syncthreads();
  float pn = sqrtf(np2);                                 // uniform per wave
  float c = dot / (pn * S.qn_l[q]);
  int p = pg * 4 + pr;
  cosM[(size_t)bd * S_ * S_ + (size_t)p * S_ + q] = c;
  float rs = c;
#pragma unroll
  for (int m = 1; m < 64; m <<= 1) rs += __shfl_xor(rs, m);
  if (q == 0) sum_q[bd * S_ + p] = rs;
  S.cp[pr][q] = c;
  __syncthreads();
  if (t < S_)
    sumpart[((size_t)bd * 16 + pg) * S_ + t] =
        S.cp[0][t] + S.cp[1][t] + S.cp[2][t] + S.cp[3][t];
}

// ---------------- maxpool block (independent: |W| taken straight from Wf)
#define HP 72                       // padded fp16 row: 144 B, 16-B aligned f16x8 groups
struct MaxpoolS {                   // 21168 B
  _Float16 ph[S_][HP];
  _Float16 qh[S_][HP];
  float w1s[H_];
  float pn2[S_], qn2[S_];
  float colp[4][S_];
};

__device__ __forceinline__ void maxpool_body(char* smem, int bid,
                                             const float* __restrict__ P,
                                             const float* __restrict__ Q,
                                             const float* __restrict__ Wf,
                                             float* __restrict__ out) {
  MaxpoolS& S = *(MaxpoolS*)smem;
  // XCD swizzle: bd = (bid&7) + 8*((bid>>3)&7); l = bid>>6
  int x = bid & 7, j = bid >> 3;
  int bd = x + 8 * (j & 7);
  int l = j >> 3;
  int b = bd >> 1, dir = bd & 1;
  int t = threadIdx.x;
  int w = t >> 6, lane = t & 63, quad = lane >> 4, col = lane & 15;
  const float* wg = Wf + (size_t)(2 + dir) * L_ * H_ + (size_t)l * H_;
  if (t < 75) {
    float4v v = *(const float4v*)&wg[4 * t];
    float4v a = {fabsf(v.x), fabsf(v.y), fabsf(v.z), fabsf(v.w)};
    *(float4v*)&S.w1s[4 * t] = a;
  }
  const float* Pb = P + (size_t)b * S_ * H2_ + dir * H_;
  const float* Qb = Q + (size_t)b * S_ * H2_ + dir * H_;
  float4v acc[4];
#pragma unroll
  for (int qt = 0; qt < 4; ++qt) acc[qt] = (float4v){0.f, 0.f, 0.f, 0.f};
  float np2a[4] = {0.f, 0.f, 0.f, 0.f};
  float nq2a[4] = {0.f, 0.f, 0.f, 0.f};
  for (int h0 = 0; h0 < H_; h0 += 64) {          // 5 chunks (last zero-padded)
    __syncthreads();
#pragma unroll
    for (int jj = 0; jj < 4; ++jj) {             // float4 staging: 4 iters/chunk
      int idx = t + 256 * jj;
      int s = idx >> 4, c4 = idx & 15;
      int h = h0 + 4 * c4;
      float4v pv = {0.f, 0.f, 0.f, 0.f}, qv = {0.f, 0.f, 0.f, 0.f};
      if (h < 297) {                             // full group valid (h+3 <= 299)
        float4v wv = *(const float4v*)&S.w1s[h];
        float4v p4 = *(const float4v*)&Pb[(size_t)s * H2_ + h];
        float4v q4 = *(const float4v*)&Qb[(size_t)s * H2_ + h];
        pv = p4 * wv;
        qv = q4 * wv;
      }
      half4v phv = __builtin_convertvector(pv, half4v);
      half4v qhv = __builtin_convertvector(qv, half4v);
      *(half4v*)&S.ph[s][4 * c4] = phv;
      *(half4v*)&S.qh[s][4 * c4] = qhv;
      // norms from the SAME fp16 values (consistent with MFMA numerator)
      float4v pf = __builtin_convertvector(phv, float4v);
      float4v qf = __builtin_convertvector(qhv, float4v);
      np2a[jj] += pf.x * pf.x + pf.y * pf.y + pf.z * pf.z + pf.w * pf.w;
      nq2a[jj] += qf.x * qf.x + qf.y * qf.y + qf.z * qf.z + qf.w * qf.w;
    }
    __syncthreads();
#pragma unroll
    for (int ks = 0; ks < 2; ++ks) {
      half8v ah = *(const half8v*)&S.ph[16 * w + col][ks * 32 + quad * 8];
#pragma unroll
      for (int qt = 0; qt < 4; ++qt) {
        half8v bh = *(const half8v*)&S.qh[16 * qt + col][ks * 32 + quad * 8];
        acc[qt] = __builtin_amdgcn_mfma_f32_16x16x32_f16(ah, bh, acc[qt], 0, 0, 0);
      }
    }
  }
#pragma unroll
  for (int jj = 0; jj < 4; ++jj) {
    float a = np2a[jj], bb = nq2a[jj];
#pragma unroll
    for (int m = 1; m < 16; m <<= 1) {
      a += __shfl_xor(a, m);
      bb += __shfl_xor(bb, m);
    }
    if ((t & 15) == 0) {
      int s = (t >> 4) + 16 * jj;
      S.pn2[s] = a;
      S.qn2[s] = bb;
    }
  }
  __syncthreads();
  // C/D: row = quad*4+r (p_local), col = lane&15 (q_local) [m89/m91 verified]
  float pnv[4];
#pragma unroll
  for (int r = 0; r < 4; ++r) pnv[r] = sqrtf(S.pn2[16 * w + quad * 4 + r]);
  float rowm[4] = {NEG_INF, NEG_INF, NEG_INF, NEG_INF};
#pragma unroll
  for (int qt = 0; qt < 4; ++qt) {
    float qnv = sqrtf(S.qn2[16 * qt + col]);
    float cmv = NEG_INF;
#pragma unroll
    for (int r = 0; r < 4; ++r) {
      float c = acc[qt][r] / (pnv[r] * qnv);    // no EPS in reference maxpool
      rowm[r] = fmaxf(rowm[r], c);
      cmv = fmaxf(cmv, c);
    }
    cmv = fmaxf(cmv, __shfl_xor(cmv, 16));
    cmv = fmaxf(cmv, __shfl_xor(cmv, 32));
    if (quad == 0) S.colp[w][16 * qt + col] = cmv;
  }
#pragma unroll
  for (int m = 1; m < 16; m <<= 1)
#pragma unroll
    for (int r = 0; r < 4; ++r) rowm[r] = fmaxf(rowm[r], __shfl_xor(rowm[r], m));
  if (col == 0) {
#pragma unroll
    for (int r = 0; r < 4; ++r) {
      int p = 16 * w + quad * 4 + r;
      out[((size_t)b * S_ + p) * ROW_ + (2 + dir) * L_ + l] = rowm[r];
    }
  }
  __syncthreads();
  if (t < S_) {
    float m0 = fmaxf(fmaxf(S.colp[0][t], S.colp[1][t]), fmaxf(S.colp[2][t], S.colp[3][t]));
    out[OUTQ_OFF + ((size_t)b * S_ + t) * ROW_ + (2 + dir) * L_ + l] = m0;
  }
}

// ---------------- outs block — EXACT r9-verified 256-thread version.
#define SG 4
struct OutsS {                      // 31264 B
  float u[600];
  float xP[SG][H_], xQ[SG][H_];
  float vmq[SG][H_], vmp[SG][H_], vxq[SG][H_], vxp[SG][H_];
  float sps[SG], sqs[SG];
};

__device__ __forceinline__ void outs_body(char* smem, int bid,
                                          const float* __restrict__ P,
                                          const float* __restrict__ Q,
                                          const float* __restrict__ w2r,
                                          const float* __restrict__ cosM,
                                          const float* __restrict__ sumpart,
                                          const float* __restrict__ sum_q,
                                          float* __restrict__ out) {
  OutsS& S = *(OutsS*)smem;
  // XCD swizzle: bd = (bid&7) + 8*((bid>>3)&7); sg = bid>>6
  int x = bid & 7, j = bid >> 3;
  int bd = x + 8 * (j & 7);
  int sg = j >> 3;
  int s0 = sg * SG;
  int b = bd >> 1, dir = bd & 1;
  int t = threadIdx.x;
  // cos staged TRANSPOSED + interleaved: cosT[k][si] = cosC, cosT[k][4+si] = cosR
  float (*cosT)[8] = (float (*)[8])&S.u[0];     // 512 floats in u[600]
  const float* cm = cosM + (size_t)bd * S_ * S_;
  for (int idx = t; idx < S_ * 8; idx += 256) {
    int k = idx >> 3, jj = idx & 7, si = jj & 3;
    cosT[k][jj] = (jj < 4) ? cm[(size_t)k * S_ + s0 + si]
                           : cm[(size_t)(s0 + si) * S_ + k];
  }
  if (t < SG) {
    float a = 0.f;
    for (int pg = 0; pg < 16; ++pg) a += sumpart[((size_t)bd * 16 + pg) * S_ + s0 + t];
    S.sps[t] = a;
    S.sqs[t] = sum_q[bd * S_ + s0 + t];
  }
  int tgt = dir ? 0 : S_ - 1;
  const float* Pb = P + (size_t)b * S_ * H2_ + dir * H_;
  const float* Qb = Q + (size_t)b * S_ * H2_ + dir * H_;
  for (int g = t; g < SG * 75; g += 256) {
    int si = g / 75, c4 = g - si * 75;
    *(float4v*)&S.xP[si][4 * c4] = *(const float4v*)&Pb[(size_t)(s0 + si) * H2_ + 4 * c4];
    *(float4v*)&S.xQ[si][4 * c4] = *(const float4v*)&Qb[(size_t)(s0 + si) * H2_ + 4 * c4];
  }
  __syncthreads();
  for (int h = t; h < H_; h += 256) {
    float amp[SG], amq[SG], axp[SG], axq[SG];
#pragma unroll
    for (int si = 0; si < SG; ++si) { amp[si] = 0.f; amq[si] = 0.f; axp[si] = NEG_INF; axq[si] = NEG_INF; }
    for (int k = 0; k < S_; k += 2) {
      float pv0 = Pb[(size_t)k * H2_ + h];
      float qv0 = Qb[(size_t)k * H2_ + h];
      float pv1 = Pb[(size_t)(k + 1) * H2_ + h];
      float qv1 = Qb[(size_t)(k + 1) * H2_ + h];
      float4v cc0 = *(const float4v*)&cosT[k][0];
      float4v cr0 = *(const float4v*)&cosT[k][4];
      float4v cc1 = *(const float4v*)&cosT[k + 1][0];
      float4v cr1 = *(const float4v*)&cosT[k + 1][4];
#pragma unroll
      for (int si = 0; si < SG; ++si) {
        float t1 = pv0 * cc0[si];
        amp[si] += t1; axp[si] = fmaxf(axp[si], t1);
        float t2 = qv0 * cr0[si];
        amq[si] += t2; axq[si] = fmaxf(axq[si], t2);
        float t3 = pv1 * cc1[si];
        amp[si] += t3; axp[si] = fmaxf(axp[si], t3);
        float t4 = qv1 * cr1[si];
        amq[si] += t4; axq[si] = fmaxf(axq[si], t4);
      }
    }
#pragma unroll
    for (int si = 0; si < SG; ++si) {
      S.vmq[si][h] = amq[si] / S.sqs[si];
      S.vmp[si][h] = amp[si] / S.sps[si];
      S.vxq[si][h] = axq[si];
      S.vxp[si][h] = axp[si];
    }
  }
  __syncthreads();
  float* tq = &S.u[0];
  float* tp = &S.u[300];
  if (t < 75) {
    *(float4v*)&tq[4 * t] = *(const float4v*)&Qb[(size_t)tgt * H2_ + 4 * t];
    *(float4v*)&tp[4 * t] = *(const float4v*)&Pb[(size_t)tgt * H2_ + 4 * t];
  }
  __syncthreads();
  // 480 jobs, lanes share l -> w2r reads are broadcast lines.
  const int wb_[6] = {0, 0, 4, 4, 6, 6};
#pragma unroll
  for (int r = 0; r < 2; ++r) {
    int job = t + 256 * r;
    if (job < 480) {
      int l = job / 24;
      int g = job - l * 24;
      int pr = g >> 2, si = g & 3;
      const float* xv = (pr & 1) ? S.xQ[si] : S.xP[si];
      const float* y;
      if (pr == 0) y = tq;
      else if (pr == 1) y = tp;
      else if (pr == 2) y = S.vmq[si];
      else if (pr == 3) y = S.vmp[si];
      else if (pr == 4) y = S.vxq[si];
      else y = S.vxp[si];
      int widx = wb_[pr] + dir;
      const float* wp = w2r + (size_t)widx * (L_ * H_) + (size_t)l * H_;   // row layout
      float a1 = 0.f, a2 = 0.f, a3 = 0.f;
      for (int h4 = 0; h4 < H_; h4 += 4) {
        float4v wv = *(const float4v*)&wp[h4];
        float4v xx = *(const float4v*)&xv[h4];
        float4v yy = *(const float4v*)&y[h4];
#pragma unroll
        for (int jj = 0; jj < 4; ++jj) {
          float wx = wv[jj] * xx[jj];
          a1 = fmaf(wx, yy[jj], a1);
          a2 = fmaf(wx, xx[jj], a2);
          a3 = fmaf(wv[jj] * yy[jj], yy[jj], a3);
        }
      }
      float den = fmaxf(sqrtf(a2) * sqrtf(a3), 1e-8f);   // EPS per _mp_cos
      float c = a1 / den;
      int s = s0 + si;
      size_t base = ((pr & 1) ? OUTQ_OFF : 0) + ((size_t)b * S_ + s) * ROW_;
      out[base + (size_t)widx * L_ + l] = c;
    }
  }
}

// ---------------- Kernel A: cos + w^2 (everything outs depends on).
__global__ __launch_bounds__(256) void kA(const float* __restrict__ P,
                                          const float* __restrict__ Q,
                                          const float* __restrict__ Wf,
                                          float* __restrict__ w2r,
                                          float* __restrict__ cosM,
                                          float* __restrict__ sumpart,
                                          float* __restrict__ sum_q) {
  extern __shared__ char smem[];
  int bid = blockIdx.x;
  if (bid < NB_COS) {
    cos_body(smem, bid, P, Q, cosM, sumpart, sum_q);
  } else {
    int i = (bid - NB_COS) * 256 + threadIdx.x;
    if (i < 8 * L_ * H_) {
      float v = Wf[i];
      w2r[i] = v * v;
    }
  }
}

// ---------------- Kernel B: maxpool ∥ outs, interleaved 5:4 per group of 9
// (2304 = 256*9 exactly) so low-issue MFMA blocks and VALU-heavy outs blocks
// co-schedule on every CU for the whole kernel.
__global__ __launch_bounds__(256) void kB(const float* __restrict__ P,
                                          const float* __restrict__ Q,
                                          const float* __restrict__ Wf,
                                          const float* __restrict__ w2r,
                                          const float* __restrict__ cosM,
                                          const float* __restrict__ sumpart,
                                          const float* __restrict__ sum_q,
                                          float* __restrict__ out) {
  extern __shared__ char smem[];
  int bid = blockIdx.x;
  int grp = bid / 9, pos = bid - grp * 9;
  if (pos < 5) {
    maxpool_body(smem, grp * 5 + pos, P, Q, Wf, out);
  } else {
    outs_body(smem, grp * 4 + (pos - 5), P, Q, w2r, cosM, sumpart, sum_q, out);
  }
}

extern "C" void kernel_launch(void* const* d_in, const int* in_sizes, int n_in,
                              void* d_out, int out_size, void* d_ws, size_t ws_size,
                              hipStream_t stream) {
  (void)out_size; (void)ws_size;
  int iw = 2;
  for (int i = 0; i < n_in; ++i) if (in_sizes[i] == 8 * L_ * H_) iw = i;
  int io[2] = {0, 1}, k = 0;
  for (int i = 0; i < n_in && k < 2; ++i) if (i != iw) io[k++] = i;
  const float* P  = (const float*)d_in[io[0]];
  const float* Q  = (const float*)d_in[io[1]];
  const float* Wf = (const float*)d_in[iw];
  float* out = (float*)d_out;

  float* ws = (float*)d_ws;             // ~1.52 MB
  float* w2r     = ws;                  // 48000
  float* cosM    = w2r + 48000;         // 262144
  float* sumpart = cosM + 262144;       // 65536 (64 bd * 16 pg * 64 q)
  float* sum_q   = sumpart + 65536;     // 4096

  size_t shB = sizeof(MaxpoolS) > sizeof(OutsS) ? sizeof(MaxpoolS) : sizeof(OutsS);
  kA<<<NB_COS + NB_W, 256, sizeof(CosS), stream>>>(P, Q, Wf, w2r, cosM, sumpart, sum_q);
  kB<<<NB_MP + NB_OUT, 256, shB, stream>>>(P, Q, Wf, w2r, cosM, sumpart, sum_q, out);
}

// Round 12
// 138.269 us; speedup vs baseline: 1.2164x; 1.2164x over previous
//
#include <hip/hip_runtime.h>

#define B_ 32
#define S_ 64
#define H_ 300
#define H2_ 600
#define L_ 20
#define ROW_ 160                    // 8 pieces * 20
#define OUTQ_OFF ((size_t)B_ * S_ * ROW_)
#define NEG_INF -3.402823466e38f

#define NB_MP 1280                  // 64 bd * 20 l   (dispatched first)
#define NB_W 188                    // 48000 / 256 rounded up
#define NB_COS 1024                 // 64 bd * 16 pg (4 p-rows each)

typedef __attribute__((ext_vector_type(8))) _Float16 half8v;   // 8 f16 = 4 VGPRs
typedef __attribute__((ext_vector_type(4))) _Float16 half4v;   // 4 f16 = 8 B
typedef __attribute__((ext_vector_type(4))) float float4v;

// ---------------- cos block: (bd, pg) -> 4 p-rows x 64 q, norms in-block.
// r9/r10-verified body; ONLY change: XCD swizzle on the bid->(bd,pg) map so
// all 16 same-bd blocks land on one XCD (Q-panel L2 reuse; maxpool's proven
// swizzle pattern). r10 k1 FETCH=26.9MB vs 9.8MB input = cross-XCD re-fetch.
struct CosS {                       // 19008 B
  float xq[S_][65];                 // stride 65: 2-way scalar reads (free)
  float xp[4][68];                  // 272 B rows, 16-B aligned, broadcast b128
  float qn_l[S_];
  float cp[4][S_];
};

__device__ __forceinline__ void cos_body(char* smem, int bid,
                                         const float* __restrict__ P,
                                         const float* __restrict__ Q,
                                         float* __restrict__ cosM,
                                         float* __restrict__ sumpart,
                                         float* __restrict__ sum_q) {
  CosS& S = *(CosS*)smem;
  // XCD swizzle: bd = (bid&7) + 8*((bid>>3)&7); pg = bid>>6  (bijective 8x8x16)
  int x = bid & 7, j = bid >> 3;
  int bd = x + 8 * (j & 7);
  int pg = bid >> 6;
  int b = bd >> 1, dir = bd & 1;
  int t = threadIdx.x;
  int q = t & 63, pr = t >> 6;
  const float* Pb = P + (size_t)b * S_ * H2_ + dir * H_;
  const float* Qb = Q + (size_t)b * S_ * H2_ + dir * H_;
  float dot = 0.f, np2 = 0.f, nq2 = 0.f;
  for (int c0 = 0; c0 < H_; c0 += 64) {          // 5 chunks (last zero-padded)
    __syncthreads();
#pragma unroll
    for (int jj = 0; jj < 4; ++jj) {             // 64 rows x 16 groups static
      int idx = t + 256 * jj;
      int s = idx >> 4, g = idx & 15;
      int h = c0 + 4 * g;
      float4v v = {0.f, 0.f, 0.f, 0.f};
      if (h < 297) v = *(const float4v*)&Qb[(size_t)s * H2_ + h];
      S.xq[s][4 * g + 0] = v.x; S.xq[s][4 * g + 1] = v.y;
      S.xq[s][4 * g + 2] = v.z; S.xq[s][4 * g + 3] = v.w;
    }
    if (t < 64) {                                // 4 rows x 16 groups static
      int s = t >> 4, g = t & 15;
      int h = c0 + 4 * g;
      float4v v = {0.f, 0.f, 0.f, 0.f};
      if (h < 297) v = *(const float4v*)&Pb[(size_t)(pg * 4 + s) * H2_ + h];
      *(float4v*)&S.xp[s][4 * g] = v;
    }
    __syncthreads();
    for (int hh = 0; hh < 64; hh += 4) {
      float4v av = *(const float4v*)&S.xp[pr][hh];       // wave-broadcast (free)
      float q0 = S.xq[q][hh + 0];
      float q1 = S.xq[q][hh + 1];
      float q2 = S.xq[q][hh + 2];
      float q3 = S.xq[q][hh + 3];
      dot = fmaf(av.x, q0, dot); dot = fmaf(av.y, q1, dot);
      dot = fmaf(av.z, q2, dot); dot = fmaf(av.w, q3, dot);
      np2 = fmaf(av.x, av.x, np2); np2 = fmaf(av.y, av.y, np2);
      np2 = fmaf(av.z, av.z, np2); np2 = fmaf(av.w, av.w, np2);
      if (pr == 0) {                                     // wave-uniform branch
        nq2 = fmaf(q0, q0, nq2); nq2 = fmaf(q1, q1, nq2);
        nq2 = fmaf(q2, q2, nq2); nq2 = fmaf(q3, q3, nq2);
      }
    }
  }
  if (pr == 0) S.qn_l[q] = sqrtf(nq2);
  __syncthreads();
  float pn = sqrtf(np2);                                 // uniform per wave
  float c = dot / (pn * S.qn_l[q]);
  int p = pg * 4 + pr;
  cosM[(size_t)bd * S_ * S_ + (size_t)p * S_ + q] = c;
  float rs = c;
#pragma unroll
  for (int m = 1; m < 64; m <<= 1) rs += __shfl_xor(rs, m);
  if (q == 0) sum_q[bd * S_ + p] = rs;
  S.cp[pr][q] = c;
  __syncthreads();
  if (t < S_)
    sumpart[((size_t)bd * 16 + pg) * S_ + t] =
        S.cp[0][t] + S.cp[1][t] + S.cp[2][t] + S.cp[3][t];
}

// ---------------- maxpool block (independent: |W| taken straight from Wf)
#define HP 72                       // padded fp16 row: 144 B, 16-B aligned f16x8 groups
struct MaxpoolS {                   // 21168 B
  _Float16 ph[S_][HP];
  _Float16 qh[S_][HP];
  float w1s[H_];
  float pn2[S_], qn2[S_];
  float colp[4][S_];
};

__device__ __forceinline__ void maxpool_body(char* smem, int bid,
                                             const float* __restrict__ P,
                                             const float* __restrict__ Q,
                                             const float* __restrict__ Wf,
                                             float* __restrict__ out) {
  MaxpoolS& S = *(MaxpoolS*)smem;
  // XCD swizzle: bd = (bid&7) + 8*((bid>>3)&7); l = bid>>6
  int x = bid & 7, j = bid >> 3;
  int bd = x + 8 * (j & 7);
  int l = j >> 3;
  int b = bd >> 1, dir = bd & 1;
  int t = threadIdx.x;
  int w = t >> 6, lane = t & 63, quad = lane >> 4, col = lane & 15;
  const float* wg = Wf + (size_t)(2 + dir) * L_ * H_ + (size_t)l * H_;
  if (t < 75) {
    float4v v = *(const float4v*)&wg[4 * t];
    float4v a = {fabsf(v.x), fabsf(v.y), fabsf(v.z), fabsf(v.w)};
    *(float4v*)&S.w1s[4 * t] = a;
  }
  const float* Pb = P + (size_t)b * S_ * H2_ + dir * H_;
  const float* Qb = Q + (size_t)b * S_ * H2_ + dir * H_;
  float4v acc[4];
#pragma unroll
  for (int qt = 0; qt < 4; ++qt) acc[qt] = (float4v){0.f, 0.f, 0.f, 0.f};
  float np2a[4] = {0.f, 0.f, 0.f, 0.f};
  float nq2a[4] = {0.f, 0.f, 0.f, 0.f};
  for (int h0 = 0; h0 < H_; h0 += 64) {          // 5 chunks (last zero-padded)
    __syncthreads();
#pragma unroll
    for (int jj = 0; jj < 4; ++jj) {             // float4 staging: 4 iters/chunk
      int idx = t + 256 * jj;
      int s = idx >> 4, c4 = idx & 15;
      int h = h0 + 4 * c4;
      float4v pv = {0.f, 0.f, 0.f, 0.f}, qv = {0.f, 0.f, 0.f, 0.f};
      if (h < 297) {                             // full group valid (h+3 <= 299)
        float4v wv = *(const float4v*)&S.w1s[h];
        float4v p4 = *(const float4v*)&Pb[(size_t)s * H2_ + h];
        float4v q4 = *(const float4v*)&Qb[(size_t)s * H2_ + h];
        pv = p4 * wv;
        qv = q4 * wv;
      }
      half4v phv = __builtin_convertvector(pv, half4v);
      half4v qhv = __builtin_convertvector(qv, half4v);
      *(half4v*)&S.ph[s][4 * c4] = phv;
      *(half4v*)&S.qh[s][4 * c4] = qhv;
      // norms from the SAME fp16 values (consistent with MFMA numerator)
      float4v pf = __builtin_convertvector(phv, float4v);
      float4v qf = __builtin_convertvector(qhv, float4v);
      np2a[jj] += pf.x * pf.x + pf.y * pf.y + pf.z * pf.z + pf.w * pf.w;
      nq2a[jj] += qf.x * qf.x + qf.y * qf.y + qf.z * qf.z + qf.w * qf.w;
    }
    __syncthreads();
#pragma unroll
    for (int ks = 0; ks < 2; ++ks) {
      half8v ah = *(const half8v*)&S.ph[16 * w + col][ks * 32 + quad * 8];
#pragma unroll
      for (int qt = 0; qt < 4; ++qt) {
        half8v bh = *(const half8v*)&S.qh[16 * qt + col][ks * 32 + quad * 8];
        acc[qt] = __builtin_amdgcn_mfma_f32_16x16x32_f16(ah, bh, acc[qt], 0, 0, 0);
      }
    }
  }
#pragma unroll
  for (int jj = 0; jj < 4; ++jj) {
    float a = np2a[jj], bb = nq2a[jj];
#pragma unroll
    for (int m = 1; m < 16; m <<= 1) {
      a += __shfl_xor(a, m);
      bb += __shfl_xor(bb, m);
    }
    if ((t & 15) == 0) {
      int s = (t >> 4) + 16 * jj;
      S.pn2[s] = a;
      S.qn2[s] = bb;
    }
  }
  __syncthreads();
  // C/D: row = quad*4+r (p_local), col = lane&15 (q_local) [m89/m91 verified]
  float pnv[4];
#pragma unroll
  for (int r = 0; r < 4; ++r) pnv[r] = sqrtf(S.pn2[16 * w + quad * 4 + r]);
  float rowm[4] = {NEG_INF, NEG_INF, NEG_INF, NEG_INF};
#pragma unroll
  for (int qt = 0; qt < 4; ++qt) {
    float qnv = sqrtf(S.qn2[16 * qt + col]);
    float cmv = NEG_INF;
#pragma unroll
    for (int r = 0; r < 4; ++r) {
      float c = acc[qt][r] / (pnv[r] * qnv);    // no EPS in reference maxpool
      rowm[r] = fmaxf(rowm[r], c);
      cmv = fmaxf(cmv, c);
    }
    cmv = fmaxf(cmv, __shfl_xor(cmv, 16));
    cmv = fmaxf(cmv, __shfl_xor(cmv, 32));
    if (quad == 0) S.colp[w][16 * qt + col] = cmv;
  }
#pragma unroll
  for (int m = 1; m < 16; m <<= 1)
#pragma unroll
    for (int r = 0; r < 4; ++r) rowm[r] = fmaxf(rowm[r], __shfl_xor(rowm[r], m));
  if (col == 0) {
#pragma unroll
    for (int r = 0; r < 4; ++r) {
      int p = 16 * w + quad * 4 + r;
      out[((size_t)b * S_ + p) * ROW_ + (2 + dir) * L_ + l] = rowm[r];
    }
  }
  __syncthreads();
  if (t < S_) {
    float m0 = fmaxf(fmaxf(S.colp[0][t], S.colp[1][t]), fmaxf(S.colp[2][t], S.colp[3][t]));
    out[OUTQ_OFF + ((size_t)b * S_ + t) * ROW_ + (2 + dir) * L_ + l] = m0;
  }
}

// ---------------- K1: maxpool first (heavy, starts early), then w^2, then cos.
__global__ __launch_bounds__(256) void k1(const float* __restrict__ P,
                                          const float* __restrict__ Q,
                                          const float* __restrict__ Wf,
                                          float* __restrict__ w2r,
                                          float* __restrict__ cosM,
                                          float* __restrict__ sumpart,
                                          float* __restrict__ sum_q,
                                          float* __restrict__ out) {
  extern __shared__ char smem[];
  int bid = blockIdx.x;
  if (bid < NB_MP) {
    maxpool_body(smem, bid, P, Q, Wf, out);
  } else if (bid < NB_MP + NB_W) {
    int i = (bid - NB_MP) * 256 + threadIdx.x;
    if (i < 8 * L_ * H_) {
      float v = Wf[i];
      w2r[i] = v * v;
    }
  } else {
    cos_body(smem, bid - (NB_MP + NB_W), P, Q, cosM, sumpart, sum_q);
  }
}

// ---------------- K2: attentive + full outputs — EXACT r10-verified 512-thread
// version (50.2 us, occupancy 51%).
#define SG 4
struct OutsS {                      // 31264 B
  float u[600];
  float xP[SG][H_], xQ[SG][H_];
  float vmq[SG][H_], vmp[SG][H_], vxq[SG][H_], vxp[SG][H_];
  float sps[SG], sqs[SG];
};

__global__ __launch_bounds__(512) void k2(const float* __restrict__ P,
                                          const float* __restrict__ Q,
                                          const float* __restrict__ w2r,
                                          const float* __restrict__ cosM,
                                          const float* __restrict__ sumpart,
                                          const float* __restrict__ sum_q,
                                          float* __restrict__ out) {
  extern __shared__ char smem[];
  OutsS& S = *(OutsS*)smem;
  int bid = blockIdx.x;
  // XCD swizzle: bd = (bid&7) + 8*((bid>>3)&7); sg = bid>>6
  int x = bid & 7, j = bid >> 3;
  int bd = x + 8 * (j & 7);
  int sg = j >> 3;
  int s0 = sg * SG;
  int b = bd >> 1, dir = bd & 1;
  int t = threadIdx.x;
  // cos staged TRANSPOSED + interleaved: cosT[k][si] = cosC, cosT[k][4+si] = cosR
  float (*cosT)[8] = (float (*)[8])&S.u[0];     // 512 floats in u[600]
  const float* cm = cosM + (size_t)bd * S_ * S_;
  {
    int k = t >> 3, jj = t & 7, si = jj & 3;    // 512 entries, one per thread
    cosT[k][jj] = (jj < 4) ? cm[(size_t)k * S_ + s0 + si]
                           : cm[(size_t)(s0 + si) * S_ + k];
  }
  if (t < SG) {
    float a = 0.f;
    for (int pg = 0; pg < 16; ++pg) a += sumpart[((size_t)bd * 16 + pg) * S_ + s0 + t];
    S.sps[t] = a;
    S.sqs[t] = sum_q[bd * S_ + s0 + t];
  }
  int tgt = dir ? 0 : S_ - 1;
  const float* Pb = P + (size_t)b * S_ * H2_ + dir * H_;
  const float* Qb = Q + (size_t)b * S_ * H2_ + dir * H_;
  if (t < SG * 75) {                            // 300 b128 pairs, single round
    int si = t / 75, c4 = t - si * 75;
    *(float4v*)&S.xP[si][4 * c4] = *(const float4v*)&Pb[(size_t)(s0 + si) * H2_ + 4 * c4];
    *(float4v*)&S.xQ[si][4 * c4] = *(const float4v*)&Qb[(size_t)(s0 + si) * H2_ + 4 * c4];
  }
  __syncthreads();
  if (t < H_) {                                 // middle: single round, h = t
    int h = t;
    float amp[SG], amq[SG], axp[SG], axq[SG];
#pragma unroll
    for (int si = 0; si < SG; ++si) { amp[si] = 0.f; amq[si] = 0.f; axp[si] = NEG_INF; axq[si] = NEG_INF; }
    for (int k = 0; k < S_; k += 2) {
      float pv0 = Pb[(size_t)k * H2_ + h];
      float qv0 = Qb[(size_t)k * H2_ + h];
      float pv1 = Pb[(size_t)(k + 1) * H2_ + h];
      float qv1 = Qb[(size_t)(k + 1) * H2_ + h];
      float4v cc0 = *(const float4v*)&cosT[k][0];
      float4v cr0 = *(const float4v*)&cosT[k][4];
      float4v cc1 = *(const float4v*)&cosT[k + 1][0];
      float4v cr1 = *(const float4v*)&cosT[k + 1][4];
#pragma unroll
      for (int si = 0; si < SG; ++si) {
        float t1 = pv0 * cc0[si];
        amp[si] += t1; axp[si] = fmaxf(axp[si], t1);
        float t2 = qv0 * cr0[si];
        amq[si] += t2; axq[si] = fmaxf(axq[si], t2);
        float t3 = pv1 * cc1[si];
        amp[si] += t3; axp[si] = fmaxf(axp[si], t3);
        float t4 = qv1 * cr1[si];
        amq[si] += t4; axq[si] = fmaxf(axq[si], t4);
      }
    }
#pragma unroll
    for (int si = 0; si < SG; ++si) {
      S.vmq[si][h] = amq[si] / S.sqs[si];
      S.vmp[si][h] = amp[si] / S.sps[si];
      S.vxq[si][h] = axq[si];
      S.vxp[si][h] = axp[si];
    }
  }
  __syncthreads();
  float* tq = &S.u[0];
  float* tp = &S.u[300];
  if (t < 75) {
    *(float4v*)&tq[4 * t] = *(const float4v*)&Qb[(size_t)tgt * H2_ + 4 * t];
    *(float4v*)&tp[4 * t] = *(const float4v*)&Pb[(size_t)tgt * H2_ + 4 * t];
  }
  __syncthreads();
  // 480 jobs, single round; lanes share l -> w2r reads are broadcast lines.
  const int wb_[6] = {0, 0, 4, 4, 6, 6};
  if (t < 480) {
    int job = t;
    int l = job / 24;
    int g = job - l * 24;
    int pr = g >> 2, si = g & 3;
    const float* xv = (pr & 1) ? S.xQ[si] : S.xP[si];
    const float* y;
    if (pr == 0) y = tq;
    else if (pr == 1) y = tp;
    else if (pr == 2) y = S.vmq[si];
    else if (pr == 3) y = S.vmp[si];
    else if (pr == 4) y = S.vxq[si];
    else y = S.vxp[si];
    int widx = wb_[pr] + dir;
    const float* wp = w2r + (size_t)widx * (L_ * H_) + (size_t)l * H_;   // row layout
    float a1 = 0.f, a2 = 0.f, a3 = 0.f;
    for (int h4 = 0; h4 < H_; h4 += 4) {
      float4v wv = *(const float4v*)&wp[h4];
      float4v xx = *(const float4v*)&xv[h4];
      float4v yy = *(const float4v*)&y[h4];
#pragma unroll
      for (int jj = 0; jj < 4; ++jj) {
        float wx = wv[jj] * xx[jj];
        a1 = fmaf(wx, yy[jj], a1);
        a2 = fmaf(wx, xx[jj], a2);
        a3 = fmaf(wv[jj] * yy[jj], yy[jj], a3);
      }
    }
    float den = fmaxf(sqrtf(a2) * sqrtf(a3), 1e-8f);   // EPS per _mp_cos
    float c = a1 / den;
    int s = s0 + si;
    size_t base = ((pr & 1) ? OUTQ_OFF : 0) + ((size_t)b * S_ + s) * ROW_;
    out[base + (size_t)widx * L_ + l] = c;
  }
}

extern "C" void kernel_launch(void* const* d_in, const int* in_sizes, int n_in,
                              void* d_out, int out_size, void* d_ws, size_t ws_size,
                              hipStream_t stream) {
  (void)out_size; (void)ws_size;
  int iw = 2;
  for (int i = 0; i < n_in; ++i) if (in_sizes[i] == 8 * L_ * H_) iw = i;
  int io[2] = {0, 1}, k = 0;
  for (int i = 0; i < n_in && k < 2; ++i) if (i != iw) io[k++] = i;
  const float* P  = (const float*)d_in[io[0]];
  const float* Q  = (const float*)d_in[io[1]];
  const float* Wf = (const float*)d_in[iw];
  float* out = (float*)d_out;

  float* ws = (float*)d_ws;             // ~1.52 MB
  float* w2r     = ws;                  // 48000
  float* cosM    = w2r + 48000;         // 262144
  float* sumpart = cosM + 262144;       // 65536 (64 bd * 16 pg * 64 q)
  float* sum_q   = sumpart + 65536;     // 4096

  size_t sh1 = sizeof(CosS) > sizeof(MaxpoolS) ? sizeof(CosS) : sizeof(MaxpoolS);
  k1<<<NB_MP + NB_W + NB_COS, 256, sh1, stream>>>(P, Q, Wf, w2r, cosM, sumpart, sum_q, out);
  k2<<<B_ * 2 * 16, 512, sizeof(OutsS), stream>>>(P, Q, w2r, cosM, sumpart, sum_q, out);
}